// Round 10
// baseline (212.966 us; speedup 1.0000x reference)
//
#include <hip/hip_runtime.h>
#include <hip/hip_bf16.h>
#include <stdint.h>

// Problem constants
#define TOK 16384   // B*N = 4*4096
#define NSEQ 4096
#define BATCH 4
#define Dm 512
#define Em 4
#define Hm 2048

typedef __attribute__((ext_vector_type(4))) float f32x4;
typedef __attribute__((ext_vector_type(4))) unsigned int u32x4;

// ---------- helpers ----------
__device__ __forceinline__ unsigned short f2bf(float f) {
    union { float f; uint32_t u; } v; v.f = f;
    uint32_t u = v.u;
    uint32_t r = (u + 0x7FFFu + ((u >> 16) & 1u)) >> 16;
    return (unsigned short)r;
}

struct cpx { float re, im; };
__device__ __forceinline__ cpx cmul(cpx a, cpx b) { return { a.re*b.re - a.im*b.im, a.re*b.im + a.im*b.re }; }
__device__ __forceinline__ cpx csub(cpx a, cpx b) { return { a.re - b.re, a.im - b.im }; }
__device__ __forceinline__ cpx cadd(cpx a, cpx b) { return { a.re + b.re, a.im + b.im }; }
__device__ __forceinline__ cpx cdiv(cpx a, cpx b) {
    float inv = 1.0f / (b.re*b.re + b.im*b.im);
    return { (a.re*b.re + a.im*b.im)*inv, (a.im*b.re - a.re*b.im)*inv };
}

__device__ __forceinline__ void mfma_bf16(f32x4& acc, u32x4 a, u32x4 b) {
    asm("v_mfma_f32_16x16x32_bf16 %0, %1, %2, %0" : "+v"(acc) : "v"(a), "v"(b));
}

#define GLOAD_LDS16(g, l) \
    __builtin_amdgcn_global_load_lds((const __attribute__((address_space(1))) unsigned int*)(g), \
                                     (__attribute__((address_space(3))) unsigned int*)(l), 16, 0, 0)

// ---------- kernel 1: fused prep = gate (blocks 0..511) + w1/w2 transpose (rest) ----------
// gate: fp64-accum routing + x->bf16. transpose: w1 (D,H)->(H,D) bf16, w2 (H,D)->(D,H) bf16.
#define GATE_BLOCKS 512
#define W1T_BLOCKS 4096   // 4 experts x 64 cblk x 16 rblk
#define W2T_BLOCKS 4096   // 4 experts x 16 cblk x 64 rblk
__global__ __launch_bounds__(256) void prep_kernel(
    const float* __restrict__ x, const float* __restrict__ gate_w, const float* __restrict__ gate_b,
    const float* __restrict__ w1, const float* __restrict__ w2,
    unsigned short* __restrict__ xbf, int* __restrict__ expert_id,
    unsigned short* __restrict__ w1t, unsigned short* __restrict__ w2t)
{
    int bid = blockIdx.x;
    if (bid < GATE_BLOCKS) {
        int wid = threadIdx.x >> 6, lane = threadIdx.x & 63;
        int t0 = (bid * 4 + wid) * 8;
        const float4* gw4 = (const float4*)gate_w;
        float4 g[8];
#pragma unroll
        for (int j = 0; j < 8; j++) g[j] = gw4[lane * 8 + j];
        double gb0 = (double)gate_b[0], gb1 = (double)gate_b[1];
        double gb2 = (double)gate_b[2], gb3 = (double)gate_b[3];

        for (int tt = 0; tt < 8; tt++) {
            int t = t0 + tt;
            const float4* x4 = (const float4*)(x + (size_t)t * Dm);
            float4 xa = x4[lane * 2], xb = x4[lane * 2 + 1];

            uint4 pk;
            pk.x = (uint32_t)f2bf(xa.x) | ((uint32_t)f2bf(xa.y) << 16);
            pk.y = (uint32_t)f2bf(xa.z) | ((uint32_t)f2bf(xa.w) << 16);
            pk.z = (uint32_t)f2bf(xb.x) | ((uint32_t)f2bf(xb.y) << 16);
            pk.w = (uint32_t)f2bf(xb.z) | ((uint32_t)f2bf(xb.w) << 16);
            *(uint4*)(xbf + (size_t)t * Dm + lane * 8) = pk;

            float xv[8] = { xa.x, xa.y, xa.z, xa.w, xb.x, xb.y, xb.z, xb.w };
            double s0 = 0, s1 = 0, s2 = 0, s3 = 0;
#pragma unroll
            for (int j = 0; j < 8; j++) {
                s0 += (double)xv[j] * (double)g[j].x;
                s1 += (double)xv[j] * (double)g[j].y;
                s2 += (double)xv[j] * (double)g[j].z;
                s3 += (double)xv[j] * (double)g[j].w;
            }
#pragma unroll
            for (int off = 1; off < 64; off <<= 1) {
                s0 += __shfl_xor(s0, off);
                s1 += __shfl_xor(s1, off);
                s2 += __shfl_xor(s2, off);
                s3 += __shfl_xor(s3, off);
            }
            if (lane == 0) {
                double l0 = s0 + gb0, l1 = s1 + gb1, l2 = s2 + gb2, l3 = s3 + gb3;
                int e = 0; double best = l0;
                if (l1 > best) { best = l1; e = 1; }
                if (l2 > best) { best = l2; e = 2; }
                if (l3 > best) { best = l3; e = 3; }
                expert_id[t] = e;
            }
        }
        return;
    }

    // transpose work
    const float* src; unsigned short* dst; int R, C, c0, r0;
    if (bid < GATE_BLOCKS + W1T_BLOCKS) {
        int idx = bid - GATE_BLOCKS;
        int e = idx >> 10, rem = idx & 1023;          // 64 cblk x 16 rblk
        src = w1 + (size_t)e * Dm * Hm; dst = w1t + (size_t)e * Hm * Dm;
        R = Dm; C = Hm;
        c0 = (rem >> 4) * 32; r0 = (rem & 15) * 32;
    } else {
        int idx = bid - GATE_BLOCKS - W1T_BLOCKS;
        int e = idx >> 10, rem = idx & 1023;          // 16 cblk x 64 rblk
        src = w2 + (size_t)e * Hm * Dm; dst = w2t + (size_t)e * Dm * Hm;
        R = Hm; C = Dm;
        c0 = (rem >> 6) * 32; r0 = (rem & 63) * 32;
    }
    __shared__ float tile[32][33];
    int tx = threadIdx.x & 31, ty = threadIdx.x >> 5;
#pragma unroll
    for (int i = 0; i < 4; i++)
        tile[ty + i * 8][tx] = src[(size_t)(r0 + ty + i * 8) * C + c0 + tx];
    __syncthreads();
#pragma unroll
    for (int i = 0; i < 4; i++)
        dst[(size_t)(c0 + ty + i * 8) * R + r0 + tx] = f2bf(tile[tx][ty + i * 8]);
}

// ---------- kernel 3: routing compaction — deterministic, atomic-free ----------
__global__ __launch_bounds__(1024) void route_kernel(
    const int* __restrict__ expert_id, int* __restrict__ counts,
    int* __restrict__ offsets, int* __restrict__ rowmap)
{
    __shared__ int wcnt[16][4];
    __shared__ int woff[16][4];
    int wid = threadIdx.x >> 6, lane = threadIdx.x & 63;
    int base = wid * 1024;

    int myeid[16], myrank[16];
    int run0 = 0, run1 = 0, run2 = 0, run3 = 0;
#pragma unroll
    for (int s = 0; s < 16; s++) {
        int e = expert_id[base + s * 64 + lane];
        myeid[s] = e;
        unsigned long long b0 = __ballot(e & 1);
        unsigned long long b1 = __ballot(e & 2);
        unsigned long long m0 = (e & 1) ? b0 : ~b0;
        unsigned long long m1 = (e & 2) ? b1 : ~b1;
        unsigned long long same = m0 & m1;
        unsigned long long below = same & ((1ull << lane) - 1ull);
        int runh = (e == 0) ? run0 : (e == 1) ? run1 : (e == 2) ? run2 : run3;
        myrank[s] = runh + (int)__popcll(below);
        run0 += (int)__popcll(~b0 & ~b1);
        run1 += (int)__popcll(b0 & ~b1);
        run2 += (int)__popcll(~b0 & b1);
        run3 += (int)__popcll(b0 & b1);
    }
    if (lane == 0) {
        wcnt[wid][0] = run0; wcnt[wid][1] = run1; wcnt[wid][2] = run2; wcnt[wid][3] = run3;
    }
    __syncthreads();
    if (threadIdx.x == 0) {
        int t0 = 0, t1 = 0, t2 = 0, t3 = 0;
        for (int w = 0; w < 16; w++) {
            woff[w][0] = t0; woff[w][1] = t1; woff[w][2] = t2; woff[w][3] = t3;
            t0 += wcnt[w][0]; t1 += wcnt[w][1]; t2 += wcnt[w][2]; t3 += wcnt[w][3];
        }
        counts[0] = t0; counts[1] = t1; counts[2] = t2; counts[3] = t3;
        int o0 = 0, o1 = t0, o2 = t0 + t1, o3 = t0 + t1 + t2;
        offsets[0] = o0; offsets[1] = o1; offsets[2] = o2; offsets[3] = o3;
        for (int w = 0; w < 16; w++) {
            woff[w][0] += o0; woff[w][1] += o1; woff[w][2] += o2; woff[w][3] += o3;
        }
    }
    __syncthreads();
#pragma unroll
    for (int s = 0; s < 16; s++) {
        int e = myeid[s];
        rowmap[woff[wid][e] + myrank[s]] = base + s * 64 + lane;
    }
}

// ---------- grouped GEMM: 128xBN tile, BK=32, 4 waves (2Mx2N), ring-3 LDS,
// ---------- counted vmcnt, race-free 2-barrier schedule (R6-proven) ----------
// BN=128: 48KB LDS, 3 blocks/CU (GEMM1).  BN=64: 36KB LDS, 4 blocks/CU (GEMM2).
// MSWAP: mblk on blockIdx.x (gx=128) so same-A siblings land on the same XCD (R8-proven low FETCH).
template<int KTOT, int NTOT, int BN, bool MSWAP, bool GATHER_A, bool GELU_EPI>
__global__ __launch_bounds__(256, 4) void gemm_kernel(
    const unsigned short* __restrict__ A, const unsigned short* __restrict__ B,
    const float* __restrict__ bias,
    const int* __restrict__ counts, const int* __restrict__ offsets,
    const int* __restrict__ rowmap,
    unsigned short* __restrict__ Hout, float* __restrict__ Cout,
    const float* __restrict__ v_w, float* __restrict__ vpart)
{
    constexpr int NT = KTOT / 32;
    constexpr int NREP = BN / 32;        // acc N-fragments per wave (4 or 2)
    constexpr int BLOADS = BN / 64;      // B staging insts per thread (2 or 1)
    int e = blockIdx.z;
    int Me = counts[e];
    int mblk = MSWAP ? blockIdx.x : blockIdx.y;
    if (mblk * 128 >= Me) return;
    int base = offsets[e];
    int nblk = MSWAP ? blockIdx.y : blockIdx.x;
    int t = threadIdx.x, wid = t >> 6, lane = t & 63;

    __shared__ __align__(16) unsigned short As[3][128 * 32];
    __shared__ __align__(16) unsigned short Bs[3][BN * 32];

    // staging: slot f covers LDS byte f*16; r=f>>2, stored granule s=f&3 holds source g=s^((r>>1)&3)
    const unsigned short* agp[2];
#pragma unroll
    for (int c = 0; c < 2; c++) {
        int f = c * 256 + t;
        int r = f >> 2;                 // 0..127
        int g = (f & 3) ^ ((r >> 1) & 3);
        int mr = mblk * 128 + r; if (mr >= Me) mr = Me - 1;
        int arow = GATHER_A ? rowmap[base + mr] : (base + mr);
        agp[c] = A + (size_t)arow * KTOT + g * 8;
    }
    const unsigned short* bgp[BLOADS];
#pragma unroll
    for (int c = 0; c < BLOADS; c++) {
        int f = c * 256 + t;
        int r = f >> 2;                 // 0..BN-1
        int g = (f & 3) ^ ((r >> 1) & 3);
        int nr = nblk * BN + r;
        bgp[c] = B + ((size_t)e * NTOT + nr) * (size_t)KTOT + g * 8;
    }

    int wm = wid >> 1, wn = wid & 1;   // 2M x 2N waves; wave tile 64 x (BN/2)
    int g = lane >> 4;
    int r0a = wm * 64 + (lane & 15);
    int r0b = wn * (BN / 2) + (lane & 15);
    int abase = r0a * 64 + ((g ^ ((r0a >> 1) & 3)) << 4);
    int bbase = r0b * 64 + ((g ^ ((r0b >> 1) & 3)) << 4);

    f32x4 acc[4][NREP] = {};

#define STAGE_T(bufi, kt) do { \
    GLOAD_LDS16(agp[0] + (kt) * 32, &As[bufi][(size_t)(0 * 4 + wid) * 512]); \
    GLOAD_LDS16(agp[1] + (kt) * 32, &As[bufi][(size_t)(1 * 4 + wid) * 512]); \
    _Pragma("unroll") \
    for (int c = 0; c < BLOADS; c++) \
        GLOAD_LDS16(bgp[c] + (kt) * 32, &Bs[bufi][(size_t)(c * 4 + wid) * 512]); \
} while (0)

    STAGE_T(0, 0);
    STAGE_T(1, 1);
    int cur = 0;
    for (int kt = 0; kt < NT; ++kt) {
        int nb = cur + 2; if (nb >= 3) nb -= 3;
        if (kt + 2 < NT) {
            STAGE_T(nb, kt + 2);      // buf freed by barrier2 of iter kt-1
            if constexpr (BN == 128) asm volatile("s_waitcnt vmcnt(8)" ::: "memory");
            else                     asm volatile("s_waitcnt vmcnt(6)" ::: "memory");
        } else if (kt + 1 < NT) {
            if constexpr (BN == 128) asm volatile("s_waitcnt vmcnt(4)" ::: "memory");
            else                     asm volatile("s_waitcnt vmcnt(3)" ::: "memory");
        } else {
            asm volatile("s_waitcnt vmcnt(0)" ::: "memory");
        }
        __builtin_amdgcn_s_barrier();  // ALL waves' tile-kt loads visible

        const char* ab = (const char*)&As[cur][0];
        const char* bb = (const char*)&Bs[cur][0];
        u32x4 av[4], bv[NREP];
#pragma unroll
        for (int m = 0; m < 4; m++) av[m] = *(const u32x4*)(ab + abase + m * 1024);
#pragma unroll
        for (int n = 0; n < NREP; n++) bv[n] = *(const u32x4*)(bb + bbase + n * 1024);
        __builtin_amdgcn_s_setprio(1);
#pragma unroll
        for (int m = 0; m < 4; m++)
#pragma unroll
            for (int n = 0; n < NREP; n++)
                mfma_bf16(acc[m][n], av[m], bv[n]);
        __builtin_amdgcn_s_setprio(0);
        asm volatile("s_waitcnt lgkmcnt(0)" ::: "memory");  // my LDS reads complete
        __builtin_amdgcn_s_barrier();  // all readers done -> buf[kt%3] reusable
        cur = (cur + 1 == 3) ? 0 : cur + 1;
    }
#undef STAGE_T

    // epilogue: C/D layout col=lane&15, row=(lane>>4)*4+j  [m89/m91 verified]
    float bb4[NREP], vw4[NREP];
#pragma unroll
    for (int n = 0; n < NREP; n++) {
        int col = nblk * BN + wn * (BN / 2) + n * 16 + (lane & 15);
        bb4[n] = bias[e * NTOT + col];
        if (!GELU_EPI) vw4[n] = v_w[col];
    }
#pragma unroll
    for (int m = 0; m < 4; m++) {
        int rbase = wm * 64 + m * 16 + ((lane >> 4) << 2);
#pragma unroll
        for (int j = 0; j < 4; j++) {
            int row = mblk * 128 + rbase + j;
            bool ok = row < Me;
            float p = 0.0f;
            int tok = 0;
            if (!GELU_EPI) tok = rowmap[base + (ok ? row : 0)];
#pragma unroll
            for (int n = 0; n < NREP; n++) {
                int col = nblk * BN + wn * (BN / 2) + n * 16 + (lane & 15);
                float v = acc[m][n][j] + bb4[n];
                if (GELU_EPI) {
                    if (ok) {
                        float u = 0.7978845608f * (v + 0.044715f * v * v * v);
                        float ex = __expf(2.0f * u);
                        float th = 1.0f - 2.0f / (ex + 1.0f);
                        float hv = 0.5f * v * (1.0f + th);
                        Hout[(size_t)(base + row) * NTOT + col] = f2bf(hv);
                    }
                } else {
                    if (ok) Cout[(size_t)tok * Dm + col] = v;
                    p += v * vw4[n];
                }
            }
            if (!GELU_EPI) {
                // reduce across the 16 lanes sharing this row
                p += __shfl_xor(p, 1); p += __shfl_xor(p, 2);
                p += __shfl_xor(p, 4); p += __shfl_xor(p, 8);
                if (ok && (lane & 15) == 0) vpart[(size_t)tok * (NTOT / BN) + nblk] = p;
            }
        }
    }
}

// ---------- kernel 5: dre = clip(sum(vpart[8]) + v_b, ±3) - 2 ----------
__global__ __launch_bounds__(256) void vdot2_kernel(
    const float4* __restrict__ vpart, const float* __restrict__ v_b, float* __restrict__ dre)
{
    int t = blockIdx.x * 256 + threadIdx.x;
    float4 a = vpart[t * 2], b = vpart[t * 2 + 1];
    float v = a.x + a.y + a.z + a.w + b.x + b.y + b.z + b.w + v_b[0];
    v = fminf(fmaxf(v, -3.0f), 3.0f);
    dre[t] = v - 2.0f;
}

// ---------- kernel 6: blocked parallel continuant scan (fwd L / bwd R) ----------
#define SDI(i) ((i) + ((i) >> 6))
__global__ __launch_bounds__(64) void scan_kernel(
    const float* __restrict__ dre, float2* __restrict__ Lf, float2* __restrict__ Rb)
{
    int b = blockIdx.x >> 1, dir = blockIdx.x & 1;
    int lane = threadIdx.x;
    __shared__ float sd[4096 + 64];
    const float* src = dre + b * NSEQ;
    for (int i = lane; i < NSEQ; i += 64)
        sd[SDI(i)] = src[dir ? (NSEQ - 1 - i) : i];
    __syncthreads();

    cpx m00 = {1, 0}, m01 = {0, 0}, m10 = {0, 0}, m11 = {1, 0};
    int s0i = lane * 64;
#pragma unroll 4
    for (int j = 0; j < 64; j++) {
        cpx d = { sd[SDI(s0i + j)], -1.0f };
        cpx n00 = csub(cmul(d, m00), m10);
        cpx n01 = csub(cmul(d, m01), m11);
        m10 = m00; m11 = m01; m00 = n00; m01 = n01;
        if ((j & 15) == 15) {
            float mx = fmaxf(fmaxf(fmaxf(fabsf(m00.re), fabsf(m00.im)), fmaxf(fabsf(m01.re), fabsf(m01.im))),
                             fmaxf(fmaxf(fabsf(m10.re), fabsf(m10.im)), fmaxf(fabsf(m11.re), fabsf(m11.im))));
            float r = 1.0f / mx;
            m00.re *= r; m00.im *= r; m01.re *= r; m01.im *= r;
            m10.re *= r; m10.im *= r; m11.re *= r; m11.im *= r;
        }
    }

#pragma unroll
    for (int off = 1; off < 64; off <<= 1) {
        cpx q00, q01, q10, q11;
        q00.re = __shfl_up(m00.re, off); q00.im = __shfl_up(m00.im, off);
        q01.re = __shfl_up(m01.re, off); q01.im = __shfl_up(m01.im, off);
        q10.re = __shfl_up(m10.re, off); q10.im = __shfl_up(m10.im, off);
        q11.re = __shfl_up(m11.re, off); q11.im = __shfl_up(m11.im, off);
        if (lane >= off) {
            cpx r00 = cadd(cmul(m00, q00), cmul(m01, q10));
            cpx r01 = cadd(cmul(m00, q01), cmul(m01, q11));
            cpx r10 = cadd(cmul(m10, q00), cmul(m11, q10));
            cpx r11 = cadd(cmul(m10, q01), cmul(m11, q11));
            m00 = r00; m01 = r01; m10 = r10; m11 = r11;
            float mx = fmaxf(fmaxf(fmaxf(fabsf(m00.re), fabsf(m00.im)), fmaxf(fabsf(m01.re), fabsf(m01.im))),
                             fmaxf(fmaxf(fabsf(m10.re), fabsf(m10.im)), fmaxf(fabsf(m11.re), fabsf(m11.im))));
            float r = 1.0f / mx;
            m00.re *= r; m00.im *= r; m01.re *= r; m01.im *= r;
            m10.re *= r; m10.im *= r; m11.re *= r; m11.im *= r;
        }
    }

    cpx e00, e10;
    e00.re = __shfl_up(m00.re, 1); e00.im = __shfl_up(m00.im, 1);
    e10.re = __shfl_up(m10.re, 1); e10.im = __shfl_up(m10.im, 1);
    if (lane == 0) { e00 = {1, 0}; e10 = {0, 0}; }

    float2* outp = dir ? Rb : Lf;
    cpx Linv = cdiv(e10, e00);
#pragma unroll 4
    for (int j = 0; j < 64; j++) {
        int p = s0i + j;
        cpx d = { sd[SDI(p)], -1.0f };
        cpx L = csub(d, Linv);
        int idx = dir ? (NSEQ - 1 - p) : p;
        outp[b * NSEQ + idx] = make_float2(L.re, L.im);
        float inv = 1.0f / (L.re * L.re + L.im * L.im);
        Linv.re = L.re * inv; Linv.im = -L.im * inv;
    }
}

// ---------- kernel 7: G, feats, spec, final add (in-place on d_out) ----------
__global__ __launch_bounds__(256) void final_kernel(
    float* __restrict__ out, const float* __restrict__ dre,
    const float2* __restrict__ Lf, const float2* __restrict__ Rb,
    const float* __restrict__ out_w, const float* __restrict__ out_b,
    const float* __restrict__ bk)
{
    int t = blockIdx.x * 2 + (threadIdx.x >> 7);
    int c = threadIdx.x & 127;
    float2 L = Lf[t], R = Rb[t];
    float dr = dre[t];
    float denr = L.x + R.x - dr;
    float deni = L.y + R.y + 1.0f;
    float inv = 1.0f / (denr * denr + deni * deni);
    float f0 = fminf(fmaxf(denr * inv, -10.0f), 10.0f);
    float f1 = fminf(fmaxf(-deni * inv, -10.0f), 10.0f);
    float bks = bk[0];
    const float4* ow0 = (const float4*)out_w;
    const float4* ow1 = (const float4*)(out_w + Dm);
    const float4* ob4 = (const float4*)out_b;
    float4* o4 = (float4*)(out + (size_t)t * Dm);
    float4 w0 = ow0[c], w1v = ow1[c], ob = ob4[c];
    float4 y = o4[c];
    y.x += bks * (f0 * w0.x + f1 * w1v.x + ob.x);
    y.y += bks * (f0 * w0.y + f1 * w1v.y + ob.y);
    y.z += bks * (f0 * w0.z + f1 * w1v.z + ob.z);
    y.w += bks * (f0 * w0.w + f1 * w1v.w + ob.w);
    o4[c] = y;
}

// ---------- workspace layout ----------
constexpr size_t OFF_XBF    = 0;                        // 16384*512*2  = 16777216
constexpr size_t OFF_W1T    = 16777216;                 // 4*2048*512*2 =  8388608
constexpr size_t OFF_W2T    = OFF_W1T + 8388608;        //              =  8388608
constexpr size_t OFF_H      = OFF_W2T + 8388608;        // 16384*2048*2 = 67108864
constexpr size_t OFF_ROWMAP = OFF_H + 67108864;         // 16384*4
constexpr size_t OFF_EID    = OFF_ROWMAP + 65536;       // 16384*4
constexpr size_t OFF_DRE    = OFF_EID + 65536;          // 16384*4
constexpr size_t OFF_LF     = OFF_DRE + 65536;          // 16384*8
constexpr size_t OFF_RB     = OFF_LF + 131072;          // 16384*8
constexpr size_t OFF_CNT    = OFF_RB + 131072;          // counts[4], offsets[4]
constexpr size_t OFF_VPART  = OFF_CNT + 64;             // 16384*8*4 = 524288

extern "C" void kernel_launch(void* const* d_in, const int* in_sizes, int n_in,
                              void* d_out, int out_size, void* d_ws, size_t ws_size,
                              hipStream_t stream)
{
    const float* x      = (const float*)d_in[0];
    const float* gate_w = (const float*)d_in[1];
    const float* gate_b = (const float*)d_in[2];
    const float* w1     = (const float*)d_in[3];
    const float* b1     = (const float*)d_in[4];
    const float* w2     = (const float*)d_in[5];
    const float* b2     = (const float*)d_in[6];
    const float* v_w    = (const float*)d_in[7];
    const float* v_b    = (const float*)d_in[8];
    const float* out_w  = (const float*)d_in[9];
    const float* out_b  = (const float*)d_in[10];
    const float* bk     = (const float*)d_in[11];
    float* out = (float*)d_out;
    char* ws = (char*)d_ws;

    unsigned short* xbf = (unsigned short*)(ws + OFF_XBF);
    unsigned short* w1t = (unsigned short*)(ws + OFF_W1T);
    unsigned short* w2t = (unsigned short*)(ws + OFF_W2T);
    unsigned short* hbf = (unsigned short*)(ws + OFF_H);
    int* rowmap  = (int*)(ws + OFF_ROWMAP);
    int* eid     = (int*)(ws + OFF_EID);
    float* dre   = (float*)(ws + OFF_DRE);
    float2* Lf   = (float2*)(ws + OFF_LF);
    float2* Rb   = (float2*)(ws + OFF_RB);
    int* counts  = (int*)(ws + OFF_CNT);
    int* offsets = counts + 4;
    float* vpart = (float*)(ws + OFF_VPART);

    (void)in_sizes; (void)n_in; (void)out_size; (void)ws_size;

    prep_kernel<<<GATE_BLOCKS + W1T_BLOCKS + W2T_BLOCKS, 256, 0, stream>>>(
        x, gate_w, gate_b, w1, w2, xbf, eid, w1t, w2t);
    route_kernel<<<1, 1024, 0, stream>>>(eid, counts, offsets, rowmap);

    // FFN1: h = gelu(x @ w1 + b1)  128x128 tile, nblk-fast (R6-proven, 74us)
    gemm_kernel<512, 2048, 128, false, true, true><<<dim3(16, 128, 4), 256, 0, stream>>>(
        xbf, w1t, b1, counts, offsets, rowmap, hbf, nullptr, nullptr, nullptr);
    // FFN2: ffn = h @ w2 + b2  128x64 tile (4 blk/CU), mblk-fast (R8-proven low FETCH)
    gemm_kernel<2048, 512, 64, true, false, false><<<dim3(128, 8, 4), 256, 0, stream>>>(
        hbf, w2t, b2, counts, offsets, rowmap, nullptr, out, v_w, vpart);

    vdot2_kernel<<<TOK / 256, 256, 0, stream>>>((const float4*)vpart, v_b, dre);
    scan_kernel<<<8, 64, 0, stream>>>(dre, Lf, Rb);
    final_kernel<<<TOK / 2, 256, 0, stream>>>(out, dre, Lf, Rb, out_w, out_b, bk);
}

// Round 11
// 185.759 us; speedup vs baseline: 1.1465x; 1.1465x over previous
//
#include <hip/hip_runtime.h>
#include <hip/hip_bf16.h>
#include <stdint.h>

// Problem constants
#define TOK 16384   // B*N = 4*4096
#define NSEQ 4096
#define BATCH 4
#define Dm 512
#define Em 4
#define Hm 2048

typedef __attribute__((ext_vector_type(4))) float f32x4;
typedef __attribute__((ext_vector_type(4))) unsigned int u32x4;

// ---------- helpers ----------
__device__ __forceinline__ unsigned short f2bf(float f) {
    union { float f; uint32_t u; } v; v.f = f;
    uint32_t u = v.u;
    uint32_t r = (u + 0x7FFFu + ((u >> 16) & 1u)) >> 16;
    return (unsigned short)r;
}

struct cpx { float re, im; };
__device__ __forceinline__ cpx cmul(cpx a, cpx b) { return { a.re*b.re - a.im*b.im, a.re*b.im + a.im*b.re }; }
__device__ __forceinline__ cpx csub(cpx a, cpx b) { return { a.re - b.re, a.im - b.im }; }
__device__ __forceinline__ cpx cadd(cpx a, cpx b) { return { a.re + b.re, a.im + b.im }; }
__device__ __forceinline__ cpx cdiv(cpx a, cpx b) {
    float inv = 1.0f / (b.re*b.re + b.im*b.im);
    return { (a.re*b.re + a.im*b.im)*inv, (a.im*b.re - a.re*b.im)*inv };
}

__device__ __forceinline__ void mfma_bf16(f32x4& acc, u32x4 a, u32x4 b) {
    asm("v_mfma_f32_16x16x32_bf16 %0, %1, %2, %0" : "+v"(acc) : "v"(a), "v"(b));
}

#define GLOAD_LDS16(g, l) \
    __builtin_amdgcn_global_load_lds((const __attribute__((address_space(1))) unsigned int*)(g), \
                                     (__attribute__((address_space(3))) unsigned int*)(l), 16, 0, 0)

// ---------- kernel 1: fused prep = gate (blocks 0..511) + w1/w2 transpose (rest) ----------
#define GATE_BLOCKS 512
#define W1T_BLOCKS 4096   // 4 experts x 64 cblk x 16 rblk
#define W2T_BLOCKS 4096   // 4 experts x 16 cblk x 64 rblk
__global__ __launch_bounds__(256) void prep_kernel(
    const float* __restrict__ x, const float* __restrict__ gate_w, const float* __restrict__ gate_b,
    const float* __restrict__ w1, const float* __restrict__ w2,
    unsigned short* __restrict__ xbf, int* __restrict__ expert_id,
    unsigned short* __restrict__ w1t, unsigned short* __restrict__ w2t)
{
    int bid = blockIdx.x;
    if (bid < GATE_BLOCKS) {
        int wid = threadIdx.x >> 6, lane = threadIdx.x & 63;
        int t0 = (bid * 4 + wid) * 8;
        const float4* gw4 = (const float4*)gate_w;
        float4 g[8];
#pragma unroll
        for (int j = 0; j < 8; j++) g[j] = gw4[lane * 8 + j];
        double gb0 = (double)gate_b[0], gb1 = (double)gate_b[1];
        double gb2 = (double)gate_b[2], gb3 = (double)gate_b[3];

        for (int tt = 0; tt < 8; tt++) {
            int t = t0 + tt;
            const float4* x4 = (const float4*)(x + (size_t)t * Dm);
            float4 xa = x4[lane * 2], xb = x4[lane * 2 + 1];

            uint4 pk;
            pk.x = (uint32_t)f2bf(xa.x) | ((uint32_t)f2bf(xa.y) << 16);
            pk.y = (uint32_t)f2bf(xa.z) | ((uint32_t)f2bf(xa.w) << 16);
            pk.z = (uint32_t)f2bf(xb.x) | ((uint32_t)f2bf(xb.y) << 16);
            pk.w = (uint32_t)f2bf(xb.z) | ((uint32_t)f2bf(xb.w) << 16);
            *(uint4*)(xbf + (size_t)t * Dm + lane * 8) = pk;

            float xv[8] = { xa.x, xa.y, xa.z, xa.w, xb.x, xb.y, xb.z, xb.w };
            double s0 = 0, s1 = 0, s2 = 0, s3 = 0;
#pragma unroll
            for (int j = 0; j < 8; j++) {
                s0 += (double)xv[j] * (double)g[j].x;
                s1 += (double)xv[j] * (double)g[j].y;
                s2 += (double)xv[j] * (double)g[j].z;
                s3 += (double)xv[j] * (double)g[j].w;
            }
#pragma unroll
            for (int off = 1; off < 64; off <<= 1) {
                s0 += __shfl_xor(s0, off);
                s1 += __shfl_xor(s1, off);
                s2 += __shfl_xor(s2, off);
                s3 += __shfl_xor(s3, off);
            }
            if (lane == 0) {
                double l0 = s0 + gb0, l1 = s1 + gb1, l2 = s2 + gb2, l3 = s3 + gb3;
                int e = 0; double best = l0;
                if (l1 > best) { best = l1; e = 1; }
                if (l2 > best) { best = l2; e = 2; }
                if (l3 > best) { best = l3; e = 3; }
                expert_id[t] = e;
            }
        }
        return;
    }

    const float* src; unsigned short* dst; int R, C, c0, r0;
    if (bid < GATE_BLOCKS + W1T_BLOCKS) {
        int idx = bid - GATE_BLOCKS;
        int e = idx >> 10, rem = idx & 1023;          // 64 cblk x 16 rblk
        src = w1 + (size_t)e * Dm * Hm; dst = w1t + (size_t)e * Hm * Dm;
        R = Dm; C = Hm;
        c0 = (rem >> 4) * 32; r0 = (rem & 15) * 32;
    } else {
        int idx = bid - GATE_BLOCKS - W1T_BLOCKS;
        int e = idx >> 10, rem = idx & 1023;          // 16 cblk x 64 rblk
        src = w2 + (size_t)e * Hm * Dm; dst = w2t + (size_t)e * Dm * Hm;
        R = Hm; C = Dm;
        c0 = (rem >> 6) * 32; r0 = (rem & 63) * 32;
    }
    __shared__ float tile[32][33];
    int tx = threadIdx.x & 31, ty = threadIdx.x >> 5;
#pragma unroll
    for (int i = 0; i < 4; i++)
        tile[ty + i * 8][tx] = src[(size_t)(r0 + ty + i * 8) * C + c0 + tx];
    __syncthreads();
#pragma unroll
    for (int i = 0; i < 4; i++)
        dst[(size_t)(c0 + ty + i * 8) * R + r0 + tx] = f2bf(tile[tx][ty + i * 8]);
}

// ---------- kernel 3: routing compaction — deterministic, atomic-free ----------
__global__ __launch_bounds__(1024) void route_kernel(
    const int* __restrict__ expert_id, int* __restrict__ counts,
    int* __restrict__ offsets, int* __restrict__ rowmap)
{
    __shared__ int wcnt[16][4];
    __shared__ int woff[16][4];
    int wid = threadIdx.x >> 6, lane = threadIdx.x & 63;
    int base = wid * 1024;

    int myeid[16], myrank[16];
    int run0 = 0, run1 = 0, run2 = 0, run3 = 0;
#pragma unroll
    for (int s = 0; s < 16; s++) {
        int e = expert_id[base + s * 64 + lane];
        myeid[s] = e;
        unsigned long long b0 = __ballot(e & 1);
        unsigned long long b1 = __ballot(e & 2);
        unsigned long long m0 = (e & 1) ? b0 : ~b0;
        unsigned long long m1 = (e & 2) ? b1 : ~b1;
        unsigned long long same = m0 & m1;
        unsigned long long below = same & ((1ull << lane) - 1ull);
        int runh = (e == 0) ? run0 : (e == 1) ? run1 : (e == 2) ? run2 : run3;
        myrank[s] = runh + (int)__popcll(below);
        run0 += (int)__popcll(~b0 & ~b1);
        run1 += (int)__popcll(b0 & ~b1);
        run2 += (int)__popcll(~b0 & b1);
        run3 += (int)__popcll(b0 & b1);
    }
    if (lane == 0) {
        wcnt[wid][0] = run0; wcnt[wid][1] = run1; wcnt[wid][2] = run2; wcnt[wid][3] = run3;
    }
    __syncthreads();
    if (threadIdx.x == 0) {
        int t0 = 0, t1 = 0, t2 = 0, t3 = 0;
        for (int w = 0; w < 16; w++) {
            woff[w][0] = t0; woff[w][1] = t1; woff[w][2] = t2; woff[w][3] = t3;
            t0 += wcnt[w][0]; t1 += wcnt[w][1]; t2 += wcnt[w][2]; t3 += wcnt[w][3];
        }
        counts[0] = t0; counts[1] = t1; counts[2] = t2; counts[3] = t3;
        int o0 = 0, o1 = t0, o2 = t0 + t1, o3 = t0 + t1 + t2;
        offsets[0] = o0; offsets[1] = o1; offsets[2] = o2; offsets[3] = o3;
        for (int w = 0; w < 16; w++) {
            woff[w][0] += o0; woff[w][1] += o1; woff[w][2] += o2; woff[w][3] += o3;
        }
    }
    __syncthreads();
#pragma unroll
    for (int s = 0; s < 16; s++) {
        int e = myeid[s];
        rowmap[woff[wid][e] + myrank[s]] = base + s * 64 + lane;
    }
}

// ---------- grouped GEMM: 128x128 tile, BK=32, 4 waves (2Mx2N), ring-3 LDS (48KB, 3 blk/CU),
// ---------- counted vmcnt, race-free 2-barrier schedule (R6/R8-proven measured optimum) ----------
// MSWAP=false (GEMM1): nblk-fast grid (R6's 73.5us).  MSWAP=true (GEMM2): mblk on blockIdx.x,
// gx=128 -> same-A siblings +128 apart == same XCD -> FETCH 142->43MB (R8-proven).
template<int KTOT, int NTOT, bool MSWAP, bool GATHER_A, bool GELU_EPI>
__global__ __launch_bounds__(256, 4) void gemm_kernel(
    const unsigned short* __restrict__ A, const unsigned short* __restrict__ B,
    const float* __restrict__ bias,
    const int* __restrict__ counts, const int* __restrict__ offsets,
    const int* __restrict__ rowmap,
    unsigned short* __restrict__ Hout, float* __restrict__ Cout,
    const float* __restrict__ v_w, float* __restrict__ vpart)
{
    constexpr int NT = KTOT / 32;
    int e = blockIdx.z;
    int Me = counts[e];
    int mblk = MSWAP ? blockIdx.x : blockIdx.y;
    if (mblk * 128 >= Me) return;
    int base = offsets[e];
    int nblk = MSWAP ? blockIdx.y : blockIdx.x;
    int t = threadIdx.x, wid = t >> 6, lane = t & 63;

    __shared__ __align__(16) unsigned short As[3][128 * 32];
    __shared__ __align__(16) unsigned short Bs[3][128 * 32];

    // staging: slot f covers LDS byte f*16; r=f>>2, stored granule s=f&3 holds source g=s^((r>>1)&3)
    const unsigned short* agp[2];
    const unsigned short* bgp[2];
#pragma unroll
    for (int c = 0; c < 2; c++) {
        int f = c * 256 + t;
        int r = f >> 2;                 // 0..127
        int g = (f & 3) ^ ((r >> 1) & 3);
        int mr = mblk * 128 + r; if (mr >= Me) mr = Me - 1;
        int arow = GATHER_A ? rowmap[base + mr] : (base + mr);
        agp[c] = A + (size_t)arow * KTOT + g * 8;
        int nr = nblk * 128 + r;
        bgp[c] = B + ((size_t)e * NTOT + nr) * (size_t)KTOT + g * 8;
    }

    int wm = wid >> 1, wn = wid & 1;   // 2M x 2N waves, wave tile 64x64
    int g = lane >> 4;
    int r0a = wm * 64 + (lane & 15);
    int r0b = wn * 64 + (lane & 15);
    int abase = r0a * 64 + ((g ^ ((r0a >> 1) & 3)) << 4);
    int bbase = r0b * 64 + ((g ^ ((r0b >> 1) & 3)) << 4);

    f32x4 acc[4][4] = {};

#define STAGE_T(bufi, kt) do { \
    _Pragma("unroll") \
    for (int c = 0; c < 2; c++) { \
        GLOAD_LDS16(agp[c] + (kt) * 32, &As[bufi][(size_t)(c * 4 + wid) * 512]); \
        GLOAD_LDS16(bgp[c] + (kt) * 32, &Bs[bufi][(size_t)(c * 4 + wid) * 512]); \
    } \
} while (0)

    STAGE_T(0, 0);                    // 4 loads/thread in flight
    STAGE_T(1, 1);                    // 8 in flight
    int cur = 0;
    for (int kt = 0; kt < NT; ++kt) {
        int nb = cur + 2; if (nb >= 3) nb -= 3;
        if (kt + 2 < NT) {
            STAGE_T(nb, kt + 2);      // 12 in flight; buf freed by barrier2 of iter kt-1
            asm volatile("s_waitcnt vmcnt(8)" ::: "memory");   // own tile-kt loads done
        } else if (kt + 1 < NT) {
            asm volatile("s_waitcnt vmcnt(4)" ::: "memory");
        } else {
            asm volatile("s_waitcnt vmcnt(0)" ::: "memory");
        }
        __builtin_amdgcn_s_barrier();  // ALL waves' tile-kt loads visible

        const char* ab = (const char*)&As[cur][0];
        const char* bb = (const char*)&Bs[cur][0];
        u32x4 av[4], bv[4];
#pragma unroll
        for (int m = 0; m < 4; m++) av[m] = *(const u32x4*)(ab + abase + m * 1024);
#pragma unroll
        for (int n = 0; n < 4; n++) bv[n] = *(const u32x4*)(bb + bbase + n * 1024);
        __builtin_amdgcn_s_setprio(1);
#pragma unroll
        for (int m = 0; m < 4; m++)
#pragma unroll
            for (int n = 0; n < 4; n++)
                mfma_bf16(acc[m][n], av[m], bv[n]);
        __builtin_amdgcn_s_setprio(0);
        asm volatile("s_waitcnt lgkmcnt(0)" ::: "memory");  // my LDS reads complete
        __builtin_amdgcn_s_barrier();  // all readers done -> buf[kt%3] reusable
        cur = (cur + 1 == 3) ? 0 : cur + 1;
    }
#undef STAGE_T

    // epilogue: C/D layout col=lane&15, row=(lane>>4)*4+j  [m89/m91 verified]
    float bb4[4], vw4[4];
#pragma unroll
    for (int n = 0; n < 4; n++) {
        int col = nblk * 128 + wn * 64 + n * 16 + (lane & 15);
        bb4[n] = bias[e * NTOT + col];
        if (!GELU_EPI) vw4[n] = v_w[col];
    }
#pragma unroll
    for (int m = 0; m < 4; m++) {
        int rbase = wm * 64 + m * 16 + ((lane >> 4) << 2);
#pragma unroll
        for (int j = 0; j < 4; j++) {
            int row = mblk * 128 + rbase + j;
            bool ok = row < Me;
            float p = 0.0f;
            int tok = 0;
            if (!GELU_EPI) tok = rowmap[base + (ok ? row : 0)];
#pragma unroll
            for (int n = 0; n < 4; n++) {
                int col = nblk * 128 + wn * 64 + n * 16 + (lane & 15);
                float v = acc[m][n][j] + bb4[n];
                if (GELU_EPI) {
                    if (ok) {
                        float u = 0.7978845608f * (v + 0.044715f * v * v * v);
                        float ex = __expf(2.0f * u);
                        float th = 1.0f - 2.0f / (ex + 1.0f);
                        float hv = 0.5f * v * (1.0f + th);
                        Hout[(size_t)(base + row) * NTOT + col] = f2bf(hv);
                    }
                } else {
                    if (ok) Cout[(size_t)tok * Dm + col] = v;
                    p += v * vw4[n];
                }
            }
            if (!GELU_EPI) {
                // reduce across the 16 lanes sharing this row (lane&15 = col index)
                p += __shfl_xor(p, 1); p += __shfl_xor(p, 2);
                p += __shfl_xor(p, 4); p += __shfl_xor(p, 8);
                if (ok && (lane & 15) == 0) vpart[(size_t)tok * 4 + nblk] = p;
            }
        }
    }
}

// ---------- kernel 5: dre = clip(sum(vpart[4]) + v_b, ±3) - 2 ----------
__global__ __launch_bounds__(256) void vdot2_kernel(
    const float4* __restrict__ vpart, const float* __restrict__ v_b, float* __restrict__ dre)
{
    int t = blockIdx.x * 256 + threadIdx.x;
    float4 p = vpart[t];
    float v = p.x + p.y + p.z + p.w + v_b[0];
    v = fminf(fmaxf(v, -3.0f), 3.0f);
    dre[t] = v - 2.0f;
}

// ---------- kernel 6: blocked parallel continuant scan (fwd L / bwd R) ----------
#define SDI(i) ((i) + ((i) >> 6))
__global__ __launch_bounds__(64) void scan_kernel(
    const float* __restrict__ dre, float2* __restrict__ Lf, float2* __restrict__ Rb)
{
    int b = blockIdx.x >> 1, dir = blockIdx.x & 1;
    int lane = threadIdx.x;
    __shared__ float sd[4096 + 64];
    const float* src = dre + b * NSEQ;
    for (int i = lane; i < NSEQ; i += 64)
        sd[SDI(i)] = src[dir ? (NSEQ - 1 - i) : i];
    __syncthreads();

    cpx m00 = {1, 0}, m01 = {0, 0}, m10 = {0, 0}, m11 = {1, 0};
    int s0i = lane * 64;
#pragma unroll 4
    for (int j = 0; j < 64; j++) {
        cpx d = { sd[SDI(s0i + j)], -1.0f };
        cpx n00 = csub(cmul(d, m00), m10);
        cpx n01 = csub(cmul(d, m01), m11);
        m10 = m00; m11 = m01; m00 = n00; m01 = n01;
        if ((j & 15) == 15) {
            float mx = fmaxf(fmaxf(fmaxf(fabsf(m00.re), fabsf(m00.im)), fmaxf(fabsf(m01.re), fabsf(m01.im))),
                             fmaxf(fmaxf(fabsf(m10.re), fabsf(m10.im)), fmaxf(fabsf(m11.re), fabsf(m11.im))));
            float r = 1.0f / mx;
            m00.re *= r; m00.im *= r; m01.re *= r; m01.im *= r;
            m10.re *= r; m10.im *= r; m11.re *= r; m11.im *= r;
        }
    }

#pragma unroll
    for (int off = 1; off < 64; off <<= 1) {
        cpx q00, q01, q10, q11;
        q00.re = __shfl_up(m00.re, off); q00.im = __shfl_up(m00.im, off);
        q01.re = __shfl_up(m01.re, off); q01.im = __shfl_up(m01.im, off);
        q10.re = __shfl_up(m10.re, off); q10.im = __shfl_up(m10.im, off);
        q11.re = __shfl_up(m11.re, off); q11.im = __shfl_up(m11.im, off);
        if (lane >= off) {
            cpx r00 = cadd(cmul(m00, q00), cmul(m01, q10));
            cpx r01 = cadd(cmul(m00, q01), cmul(m01, q11));
            cpx r10 = cadd(cmul(m10, q00), cmul(m11, q10));
            cpx r11 = cadd(cmul(m10, q01), cmul(m11, q11));
            m00 = r00; m01 = r01; m10 = r10; m11 = r11;
            float mx = fmaxf(fmaxf(fmaxf(fabsf(m00.re), fabsf(m00.im)), fmaxf(fabsf(m01.re), fabsf(m01.im))),
                             fmaxf(fmaxf(fabsf(m10.re), fabsf(m10.im)), fmaxf(fabsf(m11.re), fabsf(m11.im))));
            float r = 1.0f / mx;
            m00.re *= r; m00.im *= r; m01.re *= r; m01.im *= r;
            m10.re *= r; m10.im *= r; m11.re *= r; m11.im *= r;
        }
    }

    cpx e00, e10;
    e00.re = __shfl_up(m00.re, 1); e00.im = __shfl_up(m00.im, 1);
    e10.re = __shfl_up(m10.re, 1); e10.im = __shfl_up(m10.im, 1);
    if (lane == 0) { e00 = {1, 0}; e10 = {0, 0}; }

    float2* outp = dir ? Rb : Lf;
    cpx Linv = cdiv(e10, e00);
#pragma unroll 4
    for (int j = 0; j < 64; j++) {
        int p = s0i + j;
        cpx d = { sd[SDI(p)], -1.0f };
        cpx L = csub(d, Linv);
        int idx = dir ? (NSEQ - 1 - p) : p;
        outp[b * NSEQ + idx] = make_float2(L.re, L.im);
        float inv = 1.0f / (L.re * L.re + L.im * L.im);
        Linv.re = L.re * inv; Linv.im = -L.im * inv;
    }
}

// ---------- kernel 7: G, feats, spec, final add (in-place on d_out) ----------
__global__ __launch_bounds__(256) void final_kernel(
    float* __restrict__ out, const float* __restrict__ dre,
    const float2* __restrict__ Lf, const float2* __restrict__ Rb,
    const float* __restrict__ out_w, const float* __restrict__ out_b,
    const float* __restrict__ bk)
{
    int t = blockIdx.x * 2 + (threadIdx.x >> 7);
    int c = threadIdx.x & 127;
    float2 L = Lf[t], R = Rb[t];
    float dr = dre[t];
    float denr = L.x + R.x - dr;
    float deni = L.y + R.y + 1.0f;
    float inv = 1.0f / (denr * denr + deni * deni);
    float f0 = fminf(fmaxf(denr * inv, -10.0f), 10.0f);
    float f1 = fminf(fmaxf(-deni * inv, -10.0f), 10.0f);
    float bks = bk[0];
    const float4* ow0 = (const float4*)out_w;
    const float4* ow1 = (const float4*)(out_w + Dm);
    const float4* ob4 = (const float4*)out_b;
    float4* o4 = (float4*)(out + (size_t)t * Dm);
    float4 w0 = ow0[c], w1v = ow1[c], ob = ob4[c];
    float4 y = o4[c];
    y.x += bks * (f0 * w0.x + f1 * w1v.x + ob.x);
    y.y += bks * (f0 * w0.y + f1 * w1v.y + ob.y);
    y.z += bks * (f0 * w0.z + f1 * w1v.z + ob.z);
    y.w += bks * (f0 * w0.w + f1 * w1v.w + ob.w);
    o4[c] = y;
}

// ---------- workspace layout ----------
constexpr size_t OFF_XBF    = 0;                        // 16384*512*2  = 16777216
constexpr size_t OFF_W1T    = 16777216;                 // 4*2048*512*2 =  8388608
constexpr size_t OFF_W2T    = OFF_W1T + 8388608;        //              =  8388608
constexpr size_t OFF_H      = OFF_W2T + 8388608;        // 16384*2048*2 = 67108864
constexpr size_t OFF_ROWMAP = OFF_H + 67108864;         // 16384*4
constexpr size_t OFF_EID    = OFF_ROWMAP + 65536;       // 16384*4
constexpr size_t OFF_DRE    = OFF_EID + 65536;          // 16384*4
constexpr size_t OFF_LF     = OFF_DRE + 65536;          // 16384*8
constexpr size_t OFF_RB     = OFF_LF + 131072;          // 16384*8
constexpr size_t OFF_CNT    = OFF_RB + 131072;          // counts[4], offsets[4]
constexpr size_t OFF_VPART  = OFF_CNT + 64;             // 16384*4*4 = 262144

extern "C" void kernel_launch(void* const* d_in, const int* in_sizes, int n_in,
                              void* d_out, int out_size, void* d_ws, size_t ws_size,
                              hipStream_t stream)
{
    const float* x      = (const float*)d_in[0];
    const float* gate_w = (const float*)d_in[1];
    const float* gate_b = (const float*)d_in[2];
    const float* w1     = (const float*)d_in[3];
    const float* b1     = (const float*)d_in[4];
    const float* w2     = (const float*)d_in[5];
    const float* b2     = (const float*)d_in[6];
    const float* v_w    = (const float*)d_in[7];
    const float* v_b    = (const float*)d_in[8];
    const float* out_w  = (const float*)d_in[9];
    const float* out_b  = (const float*)d_in[10];
    const float* bk     = (const float*)d_in[11];
    float* out = (float*)d_out;
    char* ws = (char*)d_ws;

    unsigned short* xbf = (unsigned short*)(ws + OFF_XBF);
    unsigned short* w1t = (unsigned short*)(ws + OFF_W1T);
    unsigned short* w2t = (unsigned short*)(ws + OFF_W2T);
    unsigned short* hbf = (unsigned short*)(ws + OFF_H);
    int* rowmap  = (int*)(ws + OFF_ROWMAP);
    int* eid     = (int*)(ws + OFF_EID);
    float* dre   = (float*)(ws + OFF_DRE);
    float2* Lf   = (float2*)(ws + OFF_LF);
    float2* Rb   = (float2*)(ws + OFF_RB);
    int* counts  = (int*)(ws + OFF_CNT);
    int* offsets = counts + 4;
    float* vpart = (float*)(ws + OFF_VPART);

    (void)in_sizes; (void)n_in; (void)out_size; (void)ws_size;

    prep_kernel<<<GATE_BLOCKS + W1T_BLOCKS + W2T_BLOCKS, 256, 0, stream>>>(
        x, gate_w, gate_b, w1, w2, xbf, eid, w1t, w2t);
    route_kernel<<<1, 1024, 0, stream>>>(eid, counts, offsets, rowmap);

    // FFN1: h = gelu(x @ w1 + b1)  128x128, nblk-fast (R6-measured 73.5us)
    gemm_kernel<512, 2048, false, true, true><<<dim3(16, 128, 4), 256, 0, stream>>>(
        xbf, w1t, b1, counts, offsets, rowmap, hbf, nullptr, nullptr, nullptr);
    // FFN2: ffn = h @ w2 + b2  128x128, mblk-fast (R8-measured 74us, FETCH 43MB)
    gemm_kernel<2048, 512, true, false, false><<<dim3(128, 4, 4), 256, 0, stream>>>(
        hbf, w2t, b2, counts, offsets, rowmap, nullptr, out, v_w, vpart);

    vdot2_kernel<<<TOK / 256, 256, 0, stream>>>((const float4*)vpart, v_b, dre);
    scan_kernel<<<8, 64, 0, stream>>>(dre, Lf, Rb);
    final_kernel<<<TOK / 2, 256, 0, stream>>>(out, dre, Lf, Rb, out_w, out_b, bk);
}

// Round 14
// 185.516 us; speedup vs baseline: 1.1480x; 1.0013x over previous
//
#include <hip/hip_runtime.h>
#include <hip/hip_bf16.h>
#include <stdint.h>

// Problem constants
#define TOK 16384   // B*N = 4*4096
#define NSEQ 4096
#define BATCH 4
#define Dm 512
#define Em 4
#define Hm 2048

typedef __attribute__((ext_vector_type(4))) float f32x4;
typedef __attribute__((ext_vector_type(4))) unsigned int u32x4;

// ---------- helpers ----------
__device__ __forceinline__ unsigned short f2bf(float f) {
    union { float f; uint32_t u; } v; v.f = f;
    uint32_t u = v.u;
    uint32_t r = (u + 0x7FFFu + ((u >> 16) & 1u)) >> 16;
    return (unsigned short)r;
}

struct cpx { float re, im; };
__device__ __forceinline__ cpx cmul(cpx a, cpx b) { return { a.re*b.re - a.im*b.im, a.re*b.im + a.im*b.re }; }
__device__ __forceinline__ cpx csub(cpx a, cpx b) { return { a.re - b.re, a.im - b.im }; }
__device__ __forceinline__ cpx cadd(cpx a, cpx b) { return { a.re + b.re, a.im + b.im }; }
__device__ __forceinline__ cpx cdiv(cpx a, cpx b) {
    float inv = 1.0f / (b.re*b.re + b.im*b.im);
    return { (a.re*b.re + a.im*b.im)*inv, (a.im*b.re - a.re*b.im)*inv };
}

__device__ __forceinline__ void mfma_bf16(f32x4& acc, u32x4 a, u32x4 b) {
    asm("v_mfma_f32_16x16x32_bf16 %0, %1, %2, %0" : "+v"(acc) : "v"(a), "v"(b));
}

#define GLOAD_LDS16(g, l) \
    __builtin_amdgcn_global_load_lds((const __attribute__((address_space(1))) unsigned int*)(g), \
                                     (__attribute__((address_space(3))) unsigned int*)(l), 16, 0, 0)

// ---------- kernel 1: fused prep = gate (blocks 0..511) + w1/w2 transpose (rest) ----------
#define GATE_BLOCKS 512
#define W1T_BLOCKS 4096   // 4 experts x 64 cblk x 16 rblk
#define W2T_BLOCKS 4096   // 4 experts x 16 cblk x 64 rblk
__global__ __launch_bounds__(256) void prep_kernel(
    const float* __restrict__ x, const float* __restrict__ gate_w, const float* __restrict__ gate_b,
    const float* __restrict__ w1, const float* __restrict__ w2,
    unsigned short* __restrict__ xbf, int* __restrict__ expert_id,
    unsigned short* __restrict__ w1t, unsigned short* __restrict__ w2t)
{
    int bid = blockIdx.x;
    if (bid < GATE_BLOCKS) {
        int wid = threadIdx.x >> 6, lane = threadIdx.x & 63;
        int t0 = (bid * 4 + wid) * 8;
        const float4* gw4 = (const float4*)gate_w;
        float4 g[8];
#pragma unroll
        for (int j = 0; j < 8; j++) g[j] = gw4[lane * 8 + j];
        double gb0 = (double)gate_b[0], gb1 = (double)gate_b[1];
        double gb2 = (double)gate_b[2], gb3 = (double)gate_b[3];

        for (int tt = 0; tt < 8; tt++) {
            int t = t0 + tt;
            const float4* x4 = (const float4*)(x + (size_t)t * Dm);
            float4 xa = x4[lane * 2], xb = x4[lane * 2 + 1];

            uint4 pk;
            pk.x = (uint32_t)f2bf(xa.x) | ((uint32_t)f2bf(xa.y) << 16);
            pk.y = (uint32_t)f2bf(xa.z) | ((uint32_t)f2bf(xa.w) << 16);
            pk.z = (uint32_t)f2bf(xb.x) | ((uint32_t)f2bf(xb.y) << 16);
            pk.w = (uint32_t)f2bf(xb.z) | ((uint32_t)f2bf(xb.w) << 16);
            *(uint4*)(xbf + (size_t)t * Dm + lane * 8) = pk;

            float xv[8] = { xa.x, xa.y, xa.z, xa.w, xb.x, xb.y, xb.z, xb.w };
            double s0 = 0, s1 = 0, s2 = 0, s3 = 0;
#pragma unroll
            for (int j = 0; j < 8; j++) {
                s0 += (double)xv[j] * (double)g[j].x;
                s1 += (double)xv[j] * (double)g[j].y;
                s2 += (double)xv[j] * (double)g[j].z;
                s3 += (double)xv[j] * (double)g[j].w;
            }
#pragma unroll
            for (int off = 1; off < 64; off <<= 1) {
                s0 += __shfl_xor(s0, off);
                s1 += __shfl_xor(s1, off);
                s2 += __shfl_xor(s2, off);
                s3 += __shfl_xor(s3, off);
            }
            if (lane == 0) {
                double l0 = s0 + gb0, l1 = s1 + gb1, l2 = s2 + gb2, l3 = s3 + gb3;
                int e = 0; double best = l0;
                if (l1 > best) { best = l1; e = 1; }
                if (l2 > best) { best = l2; e = 2; }
                if (l3 > best) { best = l3; e = 3; }
                expert_id[t] = e;
            }
        }
        return;
    }

    const float* src; unsigned short* dst; int R, C, c0, r0;
    if (bid < GATE_BLOCKS + W1T_BLOCKS) {
        int idx = bid - GATE_BLOCKS;
        int e = idx >> 10, rem = idx & 1023;          // 64 cblk x 16 rblk
        src = w1 + (size_t)e * Dm * Hm; dst = w1t + (size_t)e * Hm * Dm;
        R = Dm; C = Hm;
        c0 = (rem >> 4) * 32; r0 = (rem & 15) * 32;
    } else {
        int idx = bid - GATE_BLOCKS - W1T_BLOCKS;
        int e = idx >> 10, rem = idx & 1023;          // 16 cblk x 64 rblk
        src = w2 + (size_t)e * Hm * Dm; dst = w2t + (size_t)e * Dm * Hm;
        R = Hm; C = Dm;
        c0 = (rem >> 6) * 32; r0 = (rem & 63) * 32;
    }
    __shared__ float tile[32][33];
    int tx = threadIdx.x & 31, ty = threadIdx.x >> 5;
#pragma unroll
    for (int i = 0; i < 4; i++)
        tile[ty + i * 8][tx] = src[(size_t)(r0 + ty + i * 8) * C + c0 + tx];
    __syncthreads();
#pragma unroll
    for (int i = 0; i < 4; i++)
        dst[(size_t)(c0 + ty + i * 8) * R + r0 + tx] = f2bf(tile[tx][ty + i * 8]);
}

// ---------- kernel 3: routing compaction — deterministic, atomic-free ----------
__global__ __launch_bounds__(1024) void route_kernel(
    const int* __restrict__ expert_id, int* __restrict__ counts,
    int* __restrict__ offsets, int* __restrict__ rowmap)
{
    __shared__ int wcnt[16][4];
    __shared__ int woff[16][4];
    int wid = threadIdx.x >> 6, lane = threadIdx.x & 63;
    int base = wid * 1024;

    int myeid[16], myrank[16];
    int run0 = 0, run1 = 0, run2 = 0, run3 = 0;
#pragma unroll
    for (int s = 0; s < 16; s++) {
        int e = expert_id[base + s * 64 + lane];
        myeid[s] = e;
        unsigned long long b0 = __ballot(e & 1);
        unsigned long long b1 = __ballot(e & 2);
        unsigned long long m0 = (e & 1) ? b0 : ~b0;
        unsigned long long m1 = (e & 2) ? b1 : ~b1;
        unsigned long long same = m0 & m1;
        unsigned long long below = same & ((1ull << lane) - 1ull);
        int runh = (e == 0) ? run0 : (e == 1) ? run1 : (e == 2) ? run2 : run3;
        myrank[s] = runh + (int)__popcll(below);
        run0 += (int)__popcll(~b0 & ~b1);
        run1 += (int)__popcll(b0 & ~b1);
        run2 += (int)__popcll(~b0 & b1);
        run3 += (int)__popcll(b0 & b1);
    }
    if (lane == 0) {
        wcnt[wid][0] = run0; wcnt[wid][1] = run1; wcnt[wid][2] = run2; wcnt[wid][3] = run3;
    }
    __syncthreads();
    if (threadIdx.x == 0) {
        int t0 = 0, t1 = 0, t2 = 0, t3 = 0;
        for (int w = 0; w < 16; w++) {
            woff[w][0] = t0; woff[w][1] = t1; woff[w][2] = t2; woff[w][3] = t3;
            t0 += wcnt[w][0]; t1 += wcnt[w][1]; t2 += wcnt[w][2]; t3 += wcnt[w][3];
        }
        counts[0] = t0; counts[1] = t1; counts[2] = t2; counts[3] = t3;
        int o0 = 0, o1 = t0, o2 = t0 + t1, o3 = t0 + t1 + t2;
        offsets[0] = o0; offsets[1] = o1; offsets[2] = o2; offsets[3] = o3;
        for (int w = 0; w < 16; w++) {
            woff[w][0] += o0; woff[w][1] += o1; woff[w][2] += o2; woff[w][3] += o3;
        }
    }
    __syncthreads();
#pragma unroll
    for (int s = 0; s < 16; s++) {
        int e = myeid[s];
        rowmap[woff[wid][e] + myrank[s]] = base + s * 64 + lane;
    }
}

// ---------- grouped GEMM: 128x128 tile, BK=32, 4 waves (2Mx2N), ring-3 LDS (48KB, 3 blk/CU),
// ---------- counted vmcnt, race-free 2-barrier schedule (R6/R8/R11-proven measured optimum) ----------
// MSWAP=false (GEMM1): nblk-fast grid.  MSWAP=true (GEMM2): mblk on blockIdx.x,
// gx=128 -> same-A siblings +128 apart == same XCD -> FETCH 142->43MB (R8-proven).
template<int KTOT, int NTOT, bool MSWAP, bool GATHER_A, bool GELU_EPI>
__global__ __launch_bounds__(256, 4) void gemm_kernel(
    const unsigned short* __restrict__ A, const unsigned short* __restrict__ B,
    const float* __restrict__ bias,
    const int* __restrict__ counts, const int* __restrict__ offsets,
    const int* __restrict__ rowmap,
    unsigned short* __restrict__ Hout, float* __restrict__ Cout,
    const float* __restrict__ v_w, float* __restrict__ vpart)
{
    constexpr int NT = KTOT / 32;
    int e = blockIdx.z;
    int Me = counts[e];
    int mblk = MSWAP ? blockIdx.x : blockIdx.y;
    if (mblk * 128 >= Me) return;
    int base = offsets[e];
    int nblk = MSWAP ? blockIdx.y : blockIdx.x;
    int t = threadIdx.x, wid = t >> 6, lane = t & 63;

    __shared__ __align__(16) unsigned short As[3][128 * 32];
    __shared__ __align__(16) unsigned short Bs[3][128 * 32];

    // staging: slot f covers LDS byte f*16; r=f>>2, stored granule s=f&3 holds source g=s^((r>>1)&3)
    const unsigned short* agp[2];
    const unsigned short* bgp[2];
#pragma unroll
    for (int c = 0; c < 2; c++) {
        int f = c * 256 + t;
        int r = f >> 2;                 // 0..127
        int g = (f & 3) ^ ((r >> 1) & 3);
        int mr = mblk * 128 + r; if (mr >= Me) mr = Me - 1;
        int arow = GATHER_A ? rowmap[base + mr] : (base + mr);
        agp[c] = A + (size_t)arow * KTOT + g * 8;
        int nr = nblk * 128 + r;
        bgp[c] = B + ((size_t)e * NTOT + nr) * (size_t)KTOT + g * 8;
    }

    int wm = wid >> 1, wn = wid & 1;   // 2M x 2N waves, wave tile 64x64
    int g = lane >> 4;
    int r0a = wm * 64 + (lane & 15);
    int r0b = wn * 64 + (lane & 15);
    int abase = r0a * 64 + ((g ^ ((r0a >> 1) & 3)) << 4);
    int bbase = r0b * 64 + ((g ^ ((r0b >> 1) & 3)) << 4);

    f32x4 acc[4][4] = {};

#define STAGE_T(bufi, kt) do { \
    _Pragma("unroll") \
    for (int c = 0; c < 2; c++) { \
        GLOAD_LDS16(agp[c] + (kt) * 32, &As[bufi][(size_t)(c * 4 + wid) * 512]); \
        GLOAD_LDS16(bgp[c] + (kt) * 32, &Bs[bufi][(size_t)(c * 4 + wid) * 512]); \
    } \
} while (0)

    STAGE_T(0, 0);                    // 4 loads/thread in flight
    STAGE_T(1, 1);                    // 8 in flight
    int cur = 0;
    for (int kt = 0; kt < NT; ++kt) {
        int nb = cur + 2; if (nb >= 3) nb -= 3;
        if (kt + 2 < NT) {
            STAGE_T(nb, kt + 2);      // 12 in flight; buf freed by barrier2 of iter kt-1
            asm volatile("s_waitcnt vmcnt(8)" ::: "memory");   // own tile-kt loads done
        } else if (kt + 1 < NT) {
            asm volatile("s_waitcnt vmcnt(4)" ::: "memory");
        } else {
            asm volatile("s_waitcnt vmcnt(0)" ::: "memory");
        }
        __builtin_amdgcn_s_barrier();  // ALL waves' tile-kt loads visible

        const char* ab = (const char*)&As[cur][0];
        const char* bb = (const char*)&Bs[cur][0];
        u32x4 av[4], bv[4];
#pragma unroll
        for (int m = 0; m < 4; m++) av[m] = *(const u32x4*)(ab + abase + m * 1024);
#pragma unroll
        for (int n = 0; n < 4; n++) bv[n] = *(const u32x4*)(bb + bbase + n * 1024);
        __builtin_amdgcn_s_setprio(1);
#pragma unroll
        for (int m = 0; m < 4; m++)
#pragma unroll
            for (int n = 0; n < 4; n++)
                mfma_bf16(acc[m][n], av[m], bv[n]);
        __builtin_amdgcn_s_setprio(0);
        asm volatile("s_waitcnt lgkmcnt(0)" ::: "memory");  // my LDS reads complete
        __builtin_amdgcn_s_barrier();  // all readers done -> buf[kt%3] reusable
        cur = (cur + 1 == 3) ? 0 : cur + 1;
    }
#undef STAGE_T

    // epilogue: C/D layout col=lane&15, row=(lane>>4)*4+j  [m89/m91 verified]
    float bb4[4], vw4[4];
#pragma unroll
    for (int n = 0; n < 4; n++) {
        int col = nblk * 128 + wn * 64 + n * 16 + (lane & 15);
        bb4[n] = bias[e * NTOT + col];
        if (!GELU_EPI) vw4[n] = v_w[col];
    }
#pragma unroll
    for (int m = 0; m < 4; m++) {
        int rbase = wm * 64 + m * 16 + ((lane >> 4) << 2);
#pragma unroll
        for (int j = 0; j < 4; j++) {
            int row = mblk * 128 + rbase + j;
            bool ok = row < Me;
            float p = 0.0f;
            int tok = 0;
            if (!GELU_EPI) tok = rowmap[base + (ok ? row : 0)];
#pragma unroll
            for (int n = 0; n < 4; n++) {
                int col = nblk * 128 + wn * 64 + n * 16 + (lane & 15);
                float v = acc[m][n][j] + bb4[n];
                if (GELU_EPI) {
                    if (ok) {
                        float u = 0.7978845608f * (v + 0.044715f * v * v * v);
                        float ex = __expf(2.0f * u);
                        float th = 1.0f - 2.0f / (ex + 1.0f);
                        float hv = 0.5f * v * (1.0f + th);
                        Hout[(size_t)(base + row) * NTOT + col] = f2bf(hv);
                    }
                } else {
                    if (ok) Cout[(size_t)tok * Dm + col] = v;
                    p += v * vw4[n];
                }
            }
            if (!GELU_EPI) {
                // reduce across the 16 lanes sharing this row (lane&15 = col index)
                p += __shfl_xor(p, 1); p += __shfl_xor(p, 2);
                p += __shfl_xor(p, 4); p += __shfl_xor(p, 8);
                if (ok && (lane & 15) == 0) vpart[(size_t)tok * 4 + nblk] = p;
            }
        }
    }
}

// ---------- kernel 5: dre = clip(sum(vpart[4]) + v_b, ±3) - 2 ----------
__global__ __launch_bounds__(256) void vdot2_kernel(
    const float4* __restrict__ vpart, const float* __restrict__ v_b, float* __restrict__ dre)
{
    int t = blockIdx.x * 256 + threadIdx.x;
    float4 p = vpart[t];
    float v = p.x + p.y + p.z + p.w + v_b[0];
    v = fminf(fmaxf(v, -3.0f), 3.0f);
    dre[t] = v - 2.0f;
}

// ---------- kernel 6: blocked parallel continuant scan (fwd L / bwd R) ----------
#define SDI(i) ((i) + ((i) >> 6))
__global__ __launch_bounds__(64) void scan_kernel(
    const float* __restrict__ dre, float2* __restrict__ Lf, float2* __restrict__ Rb)
{
    int b = blockIdx.x >> 1, dir = blockIdx.x & 1;
    int lane = threadIdx.x;
    __shared__ float sd[4096 + 64];
    const float* src = dre + b * NSEQ;
    for (int i = lane; i < NSEQ; i += 64)
        sd[SDI(i)] = src[dir ? (NSEQ - 1 - i) : i];
    __syncthreads();

    cpx m00 = {1, 0}, m01 = {0, 0}, m10 = {0, 0}, m11 = {1, 0};
    int s0i = lane * 64;
#pragma unroll 4
    for (int j = 0; j < 64; j++) {
        cpx d = { sd[SDI(s0i + j)], -1.0f };
        cpx n00 = csub(cmul(d, m00), m10);
        cpx n01 = csub(cmul(d, m01), m11);
        m10 = m00; m11 = m01; m00 = n00; m01 = n01;
        if ((j & 15) == 15) {
            float mx = fmaxf(fmaxf(fmaxf(fabsf(m00.re), fabsf(m00.im)), fmaxf(fabsf(m01.re), fabsf(m01.im))),
                             fmaxf(fmaxf(fabsf(m10.re), fabsf(m10.im)), fmaxf(fabsf(m11.re), fabsf(m11.im))));
            float r = 1.0f / mx;
            m00.re *= r; m00.im *= r; m01.re *= r; m01.im *= r;
            m10.re *= r; m10.im *= r; m11.re *= r; m11.im *= r;
        }
    }

#pragma unroll
    for (int off = 1; off < 64; off <<= 1) {
        cpx q00, q01, q10, q11;
        q00.re = __shfl_up(m00.re, off); q00.im = __shfl_up(m00.im, off);
        q01.re = __shfl_up(m01.re, off); q01.im = __shfl_up(m01.im, off);
        q10.re = __shfl_up(m10.re, off); q10.im = __shfl_up(m10.im, off);
        q11.re = __shfl_up(m11.re, off); q11.im = __shfl_up(m11.im, off);
        if (lane >= off) {
            cpx r00 = cadd(cmul(m00, q00), cmul(m01, q10));
            cpx r01 = cadd(cmul(m00, q01), cmul(m01, q11));
            cpx r10 = cadd(cmul(m10, q00), cmul(m11, q10));
            cpx r11 = cadd(cmul(m10, q01), cmul(m11, q11));
            m00 = r00; m01 = r01; m10 = r10; m11 = r11;
            float mx = fmaxf(fmaxf(fmaxf(fabsf(m00.re), fabsf(m00.im)), fmaxf(fabsf(m01.re), fabsf(m01.im))),
                             fmaxf(fmaxf(fabsf(m10.re), fabsf(m10.im)), fmaxf(fabsf(m11.re), fabsf(m11.im))));
            float r = 1.0f / mx;
            m00.re *= r; m00.im *= r; m01.re *= r; m01.im *= r;
            m10.re *= r; m10.im *= r; m11.re *= r; m11.im *= r;
        }
    }

    cpx e00, e10;
    e00.re = __shfl_up(m00.re, 1); e00.im = __shfl_up(m00.im, 1);
    e10.re = __shfl_up(m10.re, 1); e10.im = __shfl_up(m10.im, 1);
    if (lane == 0) { e00 = {1, 0}; e10 = {0, 0}; }

    float2* outp = dir ? Rb : Lf;
    cpx Linv = cdiv(e10, e00);
#pragma unroll 4
    for (int j = 0; j < 64; j++) {
        int p = s0i + j;
        cpx d = { sd[SDI(p)], -1.0f };
        cpx L = csub(d, Linv);
        int idx = dir ? (NSEQ - 1 - p) : p;
        outp[b * NSEQ + idx] = make_float2(L.re, L.im);
        float inv = 1.0f / (L.re * L.re + L.im * L.im);
        Linv.re = L.re * inv; Linv.im = -L.im * inv;
    }
}

// ---------- kernel 7: G, feats, spec, final add (in-place on d_out) ----------
__global__ __launch_bounds__(256) void final_kernel(
    float* __restrict__ out, const float* __restrict__ dre,
    const float2* __restrict__ Lf, const float2* __restrict__ Rb,
    const float* __restrict__ out_w, const float* __restrict__ out_b,
    const float* __restrict__ bk)
{
    int t = blockIdx.x * 2 + (threadIdx.x >> 7);
    int c = threadIdx.x & 127;
    float2 L = Lf[t], R = Rb[t];
    float dr = dre[t];
    float denr = L.x + R.x - dr;
    float deni = L.y + R.y + 1.0f;
    float inv = 1.0f / (denr * denr + deni * deni);
    float f0 = fminf(fmaxf(denr * inv, -10.0f), 10.0f);
    float f1 = fminf(fmaxf(-deni * inv, -10.0f), 10.0f);
    float bks = bk[0];
    const float4* ow0 = (const float4*)out_w;
    const float4* ow1 = (const float4*)(out_w + Dm);
    const float4* ob4 = (const float4*)out_b;
    float4* o4 = (float4*)(out + (size_t)t * Dm);
    float4 w0 = ow0[c], w1v = ow1[c], ob = ob4[c];
    float4 y = o4[c];
    y.x += bks * (f0 * w0.x + f1 * w1v.x + ob.x);
    y.y += bks * (f0 * w0.y + f1 * w1v.y + ob.y);
    y.z += bks * (f0 * w0.z + f1 * w1v.z + ob.z);
    y.w += bks * (f0 * w0.w + f1 * w1v.w + ob.w);
    o4[c] = y;
}

// ---------- workspace layout ----------
constexpr size_t OFF_XBF    = 0;                        // 16384*512*2  = 16777216
constexpr size_t OFF_W1T    = 16777216;                 // 4*2048*512*2 =  8388608
constexpr size_t OFF_W2T    = OFF_W1T + 8388608;        //              =  8388608
constexpr size_t OFF_H      = OFF_W2T + 8388608;        // 16384*2048*2 = 67108864
constexpr size_t OFF_ROWMAP = OFF_H + 67108864;         // 16384*4
constexpr size_t OFF_EID    = OFF_ROWMAP + 65536;       // 16384*4
constexpr size_t OFF_DRE    = OFF_EID + 65536;          // 16384*4
constexpr size_t OFF_LF     = OFF_DRE + 65536;          // 16384*8
constexpr size_t OFF_RB     = OFF_LF + 131072;          // 16384*8
constexpr size_t OFF_CNT    = OFF_RB + 131072;          // counts[4], offsets[4]
constexpr size_t OFF_VPART  = OFF_CNT + 64;             // 16384*4*4 = 262144

extern "C" void kernel_launch(void* const* d_in, const int* in_sizes, int n_in,
                              void* d_out, int out_size, void* d_ws, size_t ws_size,
                              hipStream_t stream)
{
    const float* x      = (const float*)d_in[0];
    const float* gate_w = (const float*)d_in[1];
    const float* gate_b = (const float*)d_in[2];
    const float* w1     = (const float*)d_in[3];
    const float* b1     = (const float*)d_in[4];
    const float* w2     = (const float*)d_in[5];
    const float* b2     = (const float*)d_in[6];
    const float* v_w    = (const float*)d_in[7];
    const float* v_b    = (const float*)d_in[8];
    const float* out_w  = (const float*)d_in[9];
    const float* out_b  = (const float*)d_in[10];
    const float* bk     = (const float*)d_in[11];
    float* out = (float*)d_out;
    char* ws = (char*)d_ws;

    unsigned short* xbf = (unsigned short*)(ws + OFF_XBF);
    unsigned short* w1t = (unsigned short*)(ws + OFF_W1T);
    unsigned short* w2t = (unsigned short*)(ws + OFF_W2T);
    unsigned short* hbf = (unsigned short*)(ws + OFF_H);
    int* rowmap  = (int*)(ws + OFF_ROWMAP);
    int* eid     = (int*)(ws + OFF_EID);
    float* dre   = (float*)(ws + OFF_DRE);
    float2* Lf   = (float2*)(ws + OFF_LF);
    float2* Rb   = (float2*)(ws + OFF_RB);
    int* counts  = (int*)(ws + OFF_CNT);
    int* offsets = counts + 4;
    float* vpart = (float*)(ws + OFF_VPART);

    (void)in_sizes; (void)n_in; (void)out_size; (void)ws_size;

    prep_kernel<<<GATE_BLOCKS + W1T_BLOCKS + W2T_BLOCKS, 256, 0, stream>>>(
        x, gate_w, gate_b, w1, w2, xbf, eid, w1t, w2t);
    route_kernel<<<1, 1024, 0, stream>>>(eid, counts, offsets, rowmap);

    // FFN1: h = gelu(x @ w1 + b1)  128x128, nblk-fast (R6-measured 73.5us)
    gemm_kernel<512, 2048, false, true, true><<<dim3(16, 128, 4), 256, 0, stream>>>(
        xbf, w1t, b1, counts, offsets, rowmap, hbf, nullptr, nullptr, nullptr);
    // FFN2: ffn = h @ w2 + b2  128x128, mblk-fast (R8-measured 74us, FETCH 43MB)
    gemm_kernel<2048, 512, true, false, false><<<dim3(128, 4, 4), 256, 0, stream>>>(
        hbf, w2t, b2, counts, offsets, rowmap, nullptr, out, v_w, vpart);

    vdot2_kernel<<<TOK / 256, 256, 0, stream>>>((const float4*)vpart, v_b, dre);
    scan_kernel<<<8, 64, 0, stream>>>(dre, Lf, Rb);
    final_kernel<<<TOK / 2, 256, 0, stream>>>(out, dre, Lf, Rb, out_w, out_b, bk);
}